// Round 9
// baseline (14985.559 us; speedup 1.0000x reference)
//
#include <hip/hip_runtime.h>

#define B_   64
#define T_   512
#define NE   1024
#define ND   512

typedef float f4 __attribute__((ext_vector_type(4)));

// ---------------- ws layout (floats) ----------------
#define WS_TH0   0         // th buffer 0: [64][1024]
#define WS_TH1   65536     // th buffer 1
#define WS_LAST  131072    // last_enc [64][1024]
#define WS_BAR   196608    // 8 groups x 64 slots x 32 uints = 16384 uints
#define WS_ZERO_F4 53248   // (196608 + 16384) / 4

__global__ __launch_bounds__(256) void init_ws(float4* __restrict__ ws4) {
    int i = blockIdx.x * 256 + threadIdx.x;
    if (i < WS_ZERO_F4) ws4[i] = make_float4(0.f, 0.f, 0.f, 0.f);
}

// inline, call-free tanh: 1 - 2/(e^{2x}+1)
__device__ __forceinline__ float fast_tanh(float x) {
    float e = __expf(2.0f * x);
    return 1.0f - 2.0f / (e + 1.0f);
}

// Persistent encoder: 512 blocks = 8 batch-groups(8 batches) x 64 n-blocks
// (16 neurons), 256 threads, 2 blocks/CU (different groups -> poll/MAC overlap).
// J is STREAMED from L2 each step (plain loads; ~512KB J slice per XCD stays
// L2-resident because nothing ever fences/invalidates). Register need ~45 --
// below every allocator budget observed in r4-r8, so no spills by design.
// th exchange: per-element agent-scope atomics (LLC), fence-free.
// Thread (ks=tid>>3 in [0,32), ng=tid&7): rows {nbb+2ng, +1} x 8 batches x 32k.
__global__ __launch_bounds__(256)
void enc_persist(const float* __restrict__ X, const float* __restrict__ noise,
                 const float* __restrict__ W_in, const float* __restrict__ J,
                 const float* __restrict__ in_s, const int* __restrict__ BT,
                 float* __restrict__ th0, float* __restrict__ th1,
                 float* __restrict__ last, unsigned* __restrict__ bar)
{
    __shared__ float th_lds[8192];    // 8 batches x 1024 (32 KB)
    __shared__ float red[4224];       // 32 ks x 132 (16.5 KB), stride 132: bank-uniform

    const int tid = threadIdx.x;
    const int bid = blockIdx.x;
    const int pb  = bid >> 6;          // 0..7  batch group (8 batches)
    const int nbb = (bid & 63) * 16;   // neuron base (16 neurons/block)
    const int ks  = tid >> 3;          // 0..31 k-slice
    const int ng  = tid & 7;           // 0..7  -> J rows 2ng, 2ng+1
    const int ks4 = ks * 4;

    const float* JpA = J + (size_t)(nbb + 2 * ng + 0) * NE + ks4;
    const float* JpB = JpA + NE;

    // ---- owner state: tid<128 owns (n = nbb + (tid>>3), b = pb*8 + (tid&7)) ----
    const int on  = tid >> 3;          // 0..15
    const int ob  = tid & 7;           // 0..7
    const int bg  = pb * 8 + ob;
    const int ng_ = nbb + on;
    float hreg = 0.f, w0 = 0.f, w1 = 0.f;
    int bt = -999;
    const float is0 = in_s[0], is1 = in_s[1];
    if (tid < 128) {
        w0 = W_in[ng_ * 2 + 0];
        w1 = W_in[ng_ * 2 + 1];
        bt = BT[bg];
    }

    // group step count = max BT over this group's 8 batches
    int m = 0;
    #pragma unroll
    for (int i = 0; i < 8; ++i) m = max(m, BT[pb * 8 + i]);

    unsigned* slots  = bar + pb * 2048;           // 64 slots, 128B apart
    unsigned* myslot = slots + (bid & 63) * 32;

    for (int t = 0; t < m; ++t) {
        float* __restrict__ cur = (t & 1) ? th1 : th0;
        float* __restrict__ nxt = (t & 1) ? th0 : th1;

        // ---- prefetch drive terms (immutable inputs, issued before gate) ----
        float nz = 0.f, xa = 0.f, xb = 0.f;
        if (tid < 128) {
            nz = noise[((size_t)bg * T_ + t) * NE + ng_];
            xa = X[((size_t)bg * T_ + t) * 2 + 0];
            xb = X[((size_t)bg * T_ + t) * 2 + 1];
        }

        // ---- gate: all 64 group blocks published step t-1? (1 wave, 1 slot/lane) ----
        if (t > 0) {
            if (tid < 64) {
                unsigned* sp = slots + tid * 32;
                for (;;) {
                    unsigned v = __hip_atomic_load(sp, __ATOMIC_RELAXED,
                                                   __HIP_MEMORY_SCOPE_AGENT);
                    if (__all(v >= (unsigned)t)) break;
                    __builtin_amdgcn_s_sleep(1);
                }
            }
            __syncthreads();
        }

        // ---- stage th tile (32KB) via LLC-coherent scalar loads ----
        {
            const float* src = cur + (size_t)pb * 8192;
            #pragma unroll
            for (int i = 0; i < 32; ++i)
                th_lds[tid + i * 256] =
                    __hip_atomic_load(src + tid + i * 256, __ATOMIC_RELAXED,
                                      __HIP_MEMORY_SCOPE_AGENT);
        }
        __syncthreads();

        // ---- MAC: 512 fma; J streamed from L2 (2 f4/iter), th LDS broadcast ----
        float a0[8] = {0.f, 0.f, 0.f, 0.f, 0.f, 0.f, 0.f, 0.f};
        float a1[8] = {0.f, 0.f, 0.f, 0.f, 0.f, 0.f, 0.f, 0.f};
        #pragma unroll
        for (int j = 0; j < 8; ++j) {
            const f4 jA = *(const f4*)(JpA + j * 128);
            const f4 jB = *(const f4*)(JpB + j * 128);
            #pragma unroll
            for (int b = 0; b < 8; ++b) {
                const f4 tv = *(const f4*)&th_lds[b * 1024 + ks4 + j * 128];
                a0[b] = fmaf(jA.x, tv.x, a0[b]);
                a0[b] = fmaf(jA.y, tv.y, a0[b]);
                a0[b] = fmaf(jA.z, tv.z, a0[b]);
                a0[b] = fmaf(jA.w, tv.w, a0[b]);
                a1[b] = fmaf(jB.x, tv.x, a1[b]);
                a1[b] = fmaf(jB.y, tv.y, a1[b]);
                a1[b] = fmaf(jB.z, tv.z, a1[b]);
                a1[b] = fmaf(jB.w, tv.w, a1[b]);
            }
        }

        // ---- K-reduction partials (stride 132 -> uniform bank load) ----
        *(f4*)&red[ks * 132 + (2 * ng + 0) * 8 + 0] = (f4){a0[0], a0[1], a0[2], a0[3]};
        *(f4*)&red[ks * 132 + (2 * ng + 0) * 8 + 4] = (f4){a0[4], a0[5], a0[6], a0[7]};
        *(f4*)&red[ks * 132 + (2 * ng + 1) * 8 + 0] = (f4){a1[0], a1[1], a1[2], a1[3]};
        *(f4*)&red[ks * 132 + (2 * ng + 1) * 8 + 4] = (f4){a1[4], a1[5], a1[6], a1[7]};
        __syncthreads();

        // ---- owners: reduce 32 partials (64 consecutive floats/wave: free) ----
        if (tid < 128) {
            float s = 0.f;
            #pragma unroll
            for (int k = 0; k < 32; ++k)
                s += red[k * 132 + tid];      // on*8+ob == tid
            float drive = s + nz + xa * is0 * w0 + xb * is1 * w1;
            hreg = 0.9f * hreg + 0.1f * drive;
            __hip_atomic_store(nxt + (size_t)bg * NE + ng_, fast_tanh(hreg),
                               __ATOMIC_RELAXED, __HIP_MEMORY_SCOPE_AGENT);
            if (bt == t + 1)
                __hip_atomic_store(last + (size_t)bg * NE + ng_, hreg,
                                   __ATOMIC_RELAXED, __HIP_MEMORY_SCOPE_AGENT);
        }
        __syncthreads();   // drains vmcnt: publishes at LLC before arrive

        // ---- arrive: own slot, store-release ----
        if (tid == 0)
            __hip_atomic_store(myslot, (unsigned)(t + 1),
                               __ATOMIC_RELEASE, __HIP_MEMORY_SCOPE_AGENT);
    }
}

// ---- tail ----
__global__ __launch_bounds__(256)
void wproj(const float* __restrict__ last_enc, const float* __restrict__ W,
           const float* __restrict__ bW, float* __restrict__ dec_traj)
{
    __shared__ float tl[NE];
    const int b = blockIdx.x;
    for (int k = threadIdx.x; k < NE; k += 256)
        tl[k] = tanhf(last_enc[(size_t)b * NE + k]);
    __syncthreads();
    const int wave = threadIdx.x >> 6;
    const int lane = threadIdx.x & 63;
    for (int m = wave; m < ND; m += 4) {
        const float4* Wr = (const float4*)(W + (size_t)m * NE);
        float acc = 0.f;
        #pragma unroll
        for (int it = 0; it < 4; ++it) {
            float4 wv = Wr[lane + it * 64];
            const float* tp = &tl[(lane + it * 64) * 4];
            acc = fmaf(wv.x, tp[0], acc);
            acc = fmaf(wv.y, tp[1], acc);
            acc = fmaf(wv.z, tp[2], acc);
            acc = fmaf(wv.w, tp[3], acc);
        }
        acc += __shfl_down(acc, 32); acc += __shfl_down(acc, 16);
        acc += __shfl_down(acc, 8);  acc += __shfl_down(acc, 4);
        acc += __shfl_down(acc, 2);  acc += __shfl_down(acc, 1);
        if (lane == 0) dec_traj[(size_t)b * 4 * ND + m] = acc + bW[m];
    }
}

__global__ __launch_bounds__(256)
void dec_step(const float* __restrict__ Q, float* __restrict__ dec_traj, int s)
{
    __shared__ float prev[ND];
    const int b = blockIdx.x;
    const float* pin = dec_traj + (size_t)b * 4 * ND + (size_t)(s - 1) * ND;
    for (int k = threadIdx.x; k < ND; k += 256) prev[k] = pin[k];
    __syncthreads();
    const int wave = threadIdx.x >> 6;
    const int lane = threadIdx.x & 63;
    for (int m = wave; m < ND; m += 4) {
        const float4* Qr = (const float4*)(Q + (size_t)m * ND);
        float acc = 0.f;
        #pragma unroll
        for (int it = 0; it < 2; ++it) {
            float4 qv = Qr[lane + it * 64];
            const float* tp = &prev[(lane + it * 64) * 4];
            acc = fmaf(qv.x, tp[0], acc);
            acc = fmaf(qv.y, tp[1], acc);
            acc = fmaf(qv.z, tp[2], acc);
            acc = fmaf(qv.w, tp[3], acc);
        }
        acc += __shfl_down(acc, 32); acc += __shfl_down(acc, 16);
        acc += __shfl_down(acc, 8);  acc += __shfl_down(acc, 4);
        acc += __shfl_down(acc, 2);  acc += __shfl_down(acc, 1);
        if (lane == 0)
            dec_traj[(size_t)b * 4 * ND + (size_t)s * ND + m] = acc;
    }
}

__global__ __launch_bounds__(256)
void out_proj(const float* __restrict__ dec_traj, const float* __restrict__ W_out,
              const float* __restrict__ out_s, float* __restrict__ Out)
{
    const int b = blockIdx.x;
    const int s = threadIdx.x >> 6;
    const int lane = threadIdx.x & 63;
    const float4* dp = (const float4*)(dec_traj + (size_t)b * 4 * ND + (size_t)s * ND);
    const float4* w0 = (const float4*)(W_out);
    const float4* w1 = (const float4*)(W_out + ND);
    float a0 = 0.f, a1 = 0.f;
    #pragma unroll
    for (int it = 0; it < 2; ++it) {
        float4 v  = dp[lane + it * 64];
        float4 u0 = w0[lane + it * 64];
        float4 u1 = w1[lane + it * 64];
        a0 = fmaf(v.x, u0.x, fmaf(v.y, u0.y, fmaf(v.z, u0.z, fmaf(v.w, u0.w, a0))));
        a1 = fmaf(v.x, u1.x, fmaf(v.y, u1.y, fmaf(v.z, u1.z, fmaf(v.w, u1.w, a1))));
    }
    for (int off = 32; off; off >>= 1) {
        a0 += __shfl_down(a0, off);
        a1 += __shfl_down(a1, off);
    }
    if (lane == 0) {
        Out[(size_t)b * 8 + s * 2 + 0] = out_s[0] * a0;
        Out[(size_t)b * 8 + s * 2 + 1] = out_s[1] * a1;
    }
}

extern "C" void kernel_launch(void* const* d_in, const int* in_sizes, int n_in,
                              void* d_out, int out_size, void* d_ws, size_t ws_size,
                              hipStream_t stream) {
    const float* X      = (const float*)d_in[0];
    const float* noise  = (const float*)d_in[1];
    const float* W_in   = (const float*)d_in[2];
    const float* J      = (const float*)d_in[3];
    const float* W      = (const float*)d_in[4];
    const float* bW     = (const float*)d_in[5];
    const float* Q      = (const float*)d_in[6];
    const float* W_out  = (const float*)d_in[7];
    const float* in_s   = (const float*)d_in[8];
    const float* out_s  = (const float*)d_in[9];
    const int*   BT     = (const int*)d_in[10];

    float* ws   = (float*)d_ws;
    float* th0  = ws + WS_TH0;
    float* th1  = ws + WS_TH1;
    float* last = ws + WS_LAST;
    unsigned* bar = (unsigned*)(ws + WS_BAR);

    float* out      = (float*)d_out;               // dec_traj (64,4,512)
    float* out_tail = out + (size_t)B_ * 4 * ND;   // Output (64,4,2)

    init_ws<<<208, 256, 0, stream>>>((float4*)ws);
    enc_persist<<<512, 256, 0, stream>>>(X, noise, W_in, J, in_s, BT,
                                         th0, th1, last, bar);
    wproj<<<B_, 256, 0, stream>>>(last, W, bW, out);
    for (int s = 1; s <= 3; ++s)
        dec_step<<<B_, 256, 0, stream>>>(Q, out, s);
    out_proj<<<B_, 256, 0, stream>>>(out, W_out, out_s, out_tail);
}

// Round 10
// 8280.120 us; speedup vs baseline: 1.8098x; 1.8098x over previous
//
#include <hip/hip_runtime.h>

#define B_   64
#define T_   512
#define NE   1024
#define ND   512

typedef float f4 __attribute__((ext_vector_type(4)));

// ---------------- ws layout (floats) ----------------
#define WS_TH0   0         // th buffer 0: [64][1024]
#define WS_TH1   65536     // th buffer 1
#define WS_LAST  131072    // last_enc [64][1024]
#define WS_BAR   196608    // 8 groups x 32 slots x 32 uints = 8192 uints
#define WS_ZERO_F4 51200   // (196608 + 8192) / 4

__global__ __launch_bounds__(256) void init_ws(float4* __restrict__ ws4) {
    int i = blockIdx.x * 256 + threadIdx.x;
    if (i < WS_ZERO_F4) ws4[i] = make_float4(0.f, 0.f, 0.f, 0.f);
}

// inline, call-free tanh: 1 - 2/(e^{2x}+1)
__device__ __forceinline__ float fast_tanh(float x) {
    float e = __expf(2.0f * x);
    return 1.0f - 2.0f / (e + 1.0f);
}

// Persistent encoder: 256 blocks = 8 batch-groups(8 batches) x 32 n-blocks
// (32 neurons), 256 threads, 1 block/CU (160KB LDS).
// J lives in LDS (128KB, loaded ONCE, XOR-swizzled) -- immune to the per-step
// agent acquire fence, which lets th use plain vectorized loads (fresh via
// buffer_inv) instead of per-element LLC atomics. th tile 32KB; the tiny
// K-reduction buffer overlays the th tile after the MAC phase.
// Thread (ks=tid>>3 in [0,32), ng=tid&7): 4 rows x 8 batches x 32k;
// wave folds 8 k-slices via shfl_xor, leaving 4 partials per output.
__global__ __launch_bounds__(256)
void enc_persist(const float* __restrict__ X, const float* __restrict__ noise,
                 const float* __restrict__ W_in, const float* __restrict__ J,
                 const float* __restrict__ in_s, const int* __restrict__ BT,
                 float* __restrict__ th0, float* __restrict__ th1,
                 float* __restrict__ last, unsigned* __restrict__ bar)
{
    __shared__ float J_lds[32768];    // 32 rows x 1024, XOR-swizzled (128 KB)
    __shared__ float th_lds[8192];    // 8 batches x 1024 (32 KB); red overlays [0,1056)

    const int tid = threadIdx.x;
    const int bid = blockIdx.x;
    const int pb  = bid >> 5;          // 0..7  batch group (8 batches)
    const int nbb = (bid & 31) * 32;   // neuron base (32 neurons/block)
    const int ks  = tid >> 3;          // 0..31 k-slice
    const int ng  = tid & 7;           // 0..7  -> rows 4ng..4ng+3
    const int ks4 = ks * 4;
    const int wv  = tid >> 6;          // wave 0..3

    // ---- stage J slice into LDS once (swizzled: k' = k ^ (4*(row&7))) ----
    {
        const f4* Jg = (const f4*)(J + (size_t)nbb * NE);
        for (int it = 0; it < 32; ++it) {
            int fi = tid + it * 256;           // f4 index in [0, 8192)
            int r  = fi >> 8;                  // row 0..31
            int kb = (fi & 255) * 4;           // k base
            *(f4*)&J_lds[r * 1024 + (kb ^ ((r & 7) * 4))] = Jg[fi];
        }
    }

    // per-thread swizzled k-offsets for the 4 rows
    int rb[4], s4[4];
    #pragma unroll
    for (int i = 0; i < 4; ++i) {
        int row = 4 * ng + i;
        rb[i] = row * 1024;
        s4[i] = ks4 ^ ((row & 7) * 4);
    }

    // ---- owner state: thread owns (n = nbb + (tid&31), b = pb*8 + (tid>>5)) ----
    const int on  = tid & 31;
    const int ob  = tid >> 5;
    const int bg  = pb * 8 + ob;
    const int ng_ = nbb + on;
    float hreg = 0.f;
    const float w0 = W_in[ng_ * 2 + 0];
    const float w1 = W_in[ng_ * 2 + 1];
    const int   bt = BT[bg];
    const float is0 = in_s[0], is1 = in_s[1];

    int m = 0;
    #pragma unroll
    for (int i = 0; i < 8; ++i) m = max(m, BT[pb * 8 + i]);

    unsigned* slots  = bar + pb * 1024;        // 32 slots, 128B apart
    unsigned* myslot = slots + (bid & 31) * 32;

    __syncthreads();   // J_lds ready

    for (int t = 0; t < m; ++t) {
        float* __restrict__ cur = (t & 1) ? th1 : th0;
        float* __restrict__ nxt = (t & 1) ? th0 : th1;

        // ---- prefetch drive terms into regs BEFORE gate (immutable inputs) ----
        const float nz = noise[((size_t)bg * T_ + t) * NE + ng_];
        const float xa = X[((size_t)bg * T_ + t) * 2 + 0];
        const float xb = X[((size_t)bg * T_ + t) * 2 + 1];

        // ---- gate: all 32 group blocks published step t-1? ----
        if (t > 0) {
            if (tid < 32) {
                unsigned* sp = slots + tid * 32;
                for (;;) {
                    unsigned v = __hip_atomic_load(sp, __ATOMIC_RELAXED,
                                                   __HIP_MEMORY_SCOPE_AGENT);
                    if (__all(v >= (unsigned)t)) break;
                    __builtin_amdgcn_s_sleep(1);
                }
            }
            __syncthreads();
            // invalidate L1/L2 so plain loads see LLC-fresh th.
            // J is in LDS -- unaffected; prefetches above already in regs.
            __builtin_amdgcn_fence(__ATOMIC_ACQUIRE, "agent");
        }

        // ---- stage th tile (32KB) with plain coalesced f4 loads ----
        {
            const f4* src = (const f4*)(cur + (size_t)pb * 8192);
            #pragma unroll
            for (int it = 0; it < 8; ++it)
                ((f4*)th_lds)[tid + it * 256] = src[tid + it * 256];
        }
        __syncthreads();

        // ---- MAC: 1024 fma; J swizzled-LDS, th broadcast-LDS ----
        float acc[4][8] = {};
        #pragma unroll
        for (int j = 0; j < 8; ++j) {
            f4 jv[4], tv[8];
            #pragma unroll
            for (int i = 0; i < 4; ++i)
                jv[i] = *(const f4*)&J_lds[rb[i] + s4[i] + 128 * j];
            #pragma unroll
            for (int b = 0; b < 8; ++b)
                tv[b] = *(const f4*)&th_lds[b * 1024 + ks4 + 128 * j];
            #pragma unroll
            for (int i = 0; i < 4; ++i)
                #pragma unroll
                for (int b = 0; b < 8; ++b) {
                    acc[i][b] = fmaf(jv[i].x, tv[b].x, acc[i][b]);
                    acc[i][b] = fmaf(jv[i].y, tv[b].y, acc[i][b]);
                    acc[i][b] = fmaf(jv[i].z, tv[b].z, acc[i][b]);
                    acc[i][b] = fmaf(jv[i].w, tv[b].w, acc[i][b]);
                }
        }

        // ---- fold 8 k-slices per wave via shfl_xor (lanes 3..5 = ks bits) ----
        #pragma unroll
        for (int i = 0; i < 4; ++i)
            #pragma unroll
            for (int b = 0; b < 8; ++b) {
                acc[i][b] += __shfl_xor(acc[i][b], 8);
                acc[i][b] += __shfl_xor(acc[i][b], 16);
                acc[i][b] += __shfl_xor(acc[i][b], 32);
            }

        __syncthreads();   // all MAC th-reads done -> red may overlay th_lds

        // ---- red overlay: 4 waves x 264 floats; writers = lanes with ks%8==0 ----
        if ((tid & 56) == 0) {
            float* red = th_lds;
            #pragma unroll
            for (int i = 0; i < 4; ++i) {
                *(f4*)&red[wv * 264 + (4 * ng + i) * 8 + 0] =
                    (f4){acc[i][0], acc[i][1], acc[i][2], acc[i][3]};
                *(f4*)&red[wv * 264 + (4 * ng + i) * 8 + 4] =
                    (f4){acc[i][4], acc[i][5], acc[i][6], acc[i][7]};
            }
        }
        __syncthreads();

        // ---- owners: sum 4 wave-partials, h update, publish (coalesced) ----
        {
            const float* red = th_lds;
            float s = red[0 * 264 + on * 8 + ob] + red[1 * 264 + on * 8 + ob]
                    + red[2 * 264 + on * 8 + ob] + red[3 * 264 + on * 8 + ob];
            float drive = s + nz + xa * is0 * w0 + xb * is1 * w1;
            hreg = 0.9f * hreg + 0.1f * drive;
            nxt[(size_t)bg * NE + ng_] = fast_tanh(hreg);
            if (bt == t + 1) last[(size_t)bg * NE + ng_] = hreg;
        }
        __syncthreads();   // drains vmcnt: all publishes at least in L2

        // ---- arrive: release store (wbl2 flushes dirty L2 to LLC first) ----
        if (tid == 0)
            __hip_atomic_store(myslot, (unsigned)(t + 1),
                               __ATOMIC_RELEASE, __HIP_MEMORY_SCOPE_AGENT);
    }
}

// ---- tail ----
__global__ __launch_bounds__(256)
void wproj(const float* __restrict__ last_enc, const float* __restrict__ W,
           const float* __restrict__ bW, float* __restrict__ dec_traj)
{
    __shared__ float tl[NE];
    const int b = blockIdx.x;
    for (int k = threadIdx.x; k < NE; k += 256)
        tl[k] = tanhf(last_enc[(size_t)b * NE + k]);
    __syncthreads();
    const int wave = threadIdx.x >> 6;
    const int lane = threadIdx.x & 63;
    for (int m = wave; m < ND; m += 4) {
        const float4* Wr = (const float4*)(W + (size_t)m * NE);
        float acc = 0.f;
        #pragma unroll
        for (int it = 0; it < 4; ++it) {
            float4 wv = Wr[lane + it * 64];
            const float* tp = &tl[(lane + it * 64) * 4];
            acc = fmaf(wv.x, tp[0], acc);
            acc = fmaf(wv.y, tp[1], acc);
            acc = fmaf(wv.z, tp[2], acc);
            acc = fmaf(wv.w, tp[3], acc);
        }
        acc += __shfl_down(acc, 32); acc += __shfl_down(acc, 16);
        acc += __shfl_down(acc, 8);  acc += __shfl_down(acc, 4);
        acc += __shfl_down(acc, 2);  acc += __shfl_down(acc, 1);
        if (lane == 0) dec_traj[(size_t)b * 4 * ND + m] = acc + bW[m];
    }
}

__global__ __launch_bounds__(256)
void dec_step(const float* __restrict__ Q, float* __restrict__ dec_traj, int s)
{
    __shared__ float prev[ND];
    const int b = blockIdx.x;
    const float* pin = dec_traj + (size_t)b * 4 * ND + (size_t)(s - 1) * ND;
    for (int k = threadIdx.x; k < ND; k += 256) prev[k] = pin[k];
    __syncthreads();
    const int wave = threadIdx.x >> 6;
    const int lane = threadIdx.x & 63;
    for (int m = wave; m < ND; m += 4) {
        const float4* Qr = (const float4*)(Q + (size_t)m * ND);
        float acc = 0.f;
        #pragma unroll
        for (int it = 0; it < 2; ++it) {
            float4 qv = Qr[lane + it * 64];
            const float* tp = &prev[(lane + it * 64) * 4];
            acc = fmaf(qv.x, tp[0], acc);
            acc = fmaf(qv.y, tp[1], acc);
            acc = fmaf(qv.z, tp[2], acc);
            acc = fmaf(qv.w, tp[3], acc);
        }
        acc += __shfl_down(acc, 32); acc += __shfl_down(acc, 16);
        acc += __shfl_down(acc, 8);  acc += __shfl_down(acc, 4);
        acc += __shfl_down(acc, 2);  acc += __shfl_down(acc, 1);
        if (lane == 0)
            dec_traj[(size_t)b * 4 * ND + (size_t)s * ND + m] = acc;
    }
}

__global__ __launch_bounds__(256)
void out_proj(const float* __restrict__ dec_traj, const float* __restrict__ W_out,
              const float* __restrict__ out_s, float* __restrict__ Out)
{
    const int b = blockIdx.x;
    const int s = threadIdx.x >> 6;
    const int lane = threadIdx.x & 63;
    const float4* dp = (const float4*)(dec_traj + (size_t)b * 4 * ND + (size_t)s * ND);
    const float4* w0 = (const float4*)(W_out);
    const float4* w1 = (const float4*)(W_out + ND);
    float a0 = 0.f, a1 = 0.f;
    #pragma unroll
    for (int it = 0; it < 2; ++it) {
        float4 v  = dp[lane + it * 64];
        float4 u0 = w0[lane + it * 64];
        float4 u1 = w1[lane + it * 64];
        a0 = fmaf(v.x, u0.x, fmaf(v.y, u0.y, fmaf(v.z, u0.z, fmaf(v.w, u0.w, a0))));
        a1 = fmaf(v.x, u1.x, fmaf(v.y, u1.y, fmaf(v.z, u1.z, fmaf(v.w, u1.w, a1))));
    }
    for (int off = 32; off; off >>= 1) {
        a0 += __shfl_down(a0, off);
        a1 += __shfl_down(a1, off);
    }
    if (lane == 0) {
        Out[(size_t)b * 8 + s * 2 + 0] = out_s[0] * a0;
        Out[(size_t)b * 8 + s * 2 + 1] = out_s[1] * a1;
    }
}

extern "C" void kernel_launch(void* const* d_in, const int* in_sizes, int n_in,
                              void* d_out, int out_size, void* d_ws, size_t ws_size,
                              hipStream_t stream) {
    const float* X      = (const float*)d_in[0];
    const float* noise  = (const float*)d_in[1];
    const float* W_in   = (const float*)d_in[2];
    const float* J      = (const float*)d_in[3];
    const float* W      = (const float*)d_in[4];
    const float* bW     = (const float*)d_in[5];
    const float* Q      = (const float*)d_in[6];
    const float* W_out  = (const float*)d_in[7];
    const float* in_s   = (const float*)d_in[8];
    const float* out_s  = (const float*)d_in[9];
    const int*   BT     = (const int*)d_in[10];

    float* ws   = (float*)d_ws;
    float* th0  = ws + WS_TH0;
    float* th1  = ws + WS_TH1;
    float* last = ws + WS_LAST;
    unsigned* bar = (unsigned*)(ws + WS_BAR);

    float* out      = (float*)d_out;               // dec_traj (64,4,512)
    float* out_tail = out + (size_t)B_ * 4 * ND;   // Output (64,4,2)

    init_ws<<<200, 256, 0, stream>>>((float4*)ws);
    enc_persist<<<256, 256, 0, stream>>>(X, noise, W_in, J, in_s, BT,
                                         th0, th1, last, bar);
    wproj<<<B_, 256, 0, stream>>>(last, W, bW, out);
    for (int s = 1; s <= 3; ++s)
        dec_step<<<B_, 256, 0, stream>>>(Q, out, s);
    out_proj<<<B_, 256, 0, stream>>>(out, W_out, out_s, out_tail);
}

// Round 11
// 4664.941 us; speedup vs baseline: 3.2124x; 1.7750x over previous
//
#include <hip/hip_runtime.h>

#define B_   64
#define T_   512
#define NE   1024
#define ND   512

typedef float f4 __attribute__((ext_vector_type(4)));

// ---------------- ws layout (floats) ----------------
#define WS_TH0   0         // th buffer 0: [64][1024]
#define WS_TH1   65536     // th buffer 1
#define WS_LAST  131072    // last_enc [64][1024]
#define WS_BAR   196608    // 8 groups x 32 slots x 32 uints = 8192 uints
#define WS_ZERO_F4 51200   // (196608 + 8192) / 4

__global__ __launch_bounds__(256) void init_ws(float4* __restrict__ ws4) {
    int i = blockIdx.x * 256 + threadIdx.x;
    if (i < WS_ZERO_F4) ws4[i] = make_float4(0.f, 0.f, 0.f, 0.f);
}

// inline, call-free tanh: 1 - 2/(e^{2x}+1)
__device__ __forceinline__ float fast_tanh(float x) {
    float e = __expf(2.0f * x);
    return 1.0f - 2.0f / (e + 1.0f);
}

// Persistent encoder: 256 blocks = 8 batch-groups(8 batches) x 32 n-blocks
// (32 neurons), 512 threads (2 waves/SIMD), 1 block/CU (160KB LDS).
// J in LDS (128KB, staged once, swizzle key 4*((row>>1)&7) -> every MAC read
// is 2 lanes/bank-group = free). th exchange is FENCE-FREE: 8B agent-scope
// atomic loads/stores straight to LLC; L2 never dirtied or invalidated, so
// the release-arrive is cheap (r10's per-step inv+wbl2 was the 2x killer).
// Thread (ks=tid>>4 in [0,32), ng=tid&15): rows {2ng,2ng+1} x 8 batches x 32k.
// K-reduce: shfl_xor over the wave's 2 ks-bits -> 8 wave-partials in a
// stride-33 scalar red overlay (conflict-free) -> owner sums 8.
__global__ __launch_bounds__(512)
void enc_persist(const float* __restrict__ X, const float* __restrict__ noise,
                 const float* __restrict__ W_in, const float* __restrict__ J,
                 const float* __restrict__ in_s, const int* __restrict__ BT,
                 float* __restrict__ th0, float* __restrict__ th1,
                 float* __restrict__ last, unsigned* __restrict__ bar)
{
    __shared__ float J_lds[32768];    // 32 rows x 1024, swizzled (128 KB)
    __shared__ float th_lds[8192];    // 8 batches x 1024 (32 KB); red overlays [0,2112)

    const int tid = threadIdx.x;
    const int bid = blockIdx.x;
    const int pb  = bid >> 5;          // 0..7  batch group (8 batches)
    const int nbb = (bid & 31) * 32;   // neuron base (32 neurons/block)
    const int ks  = tid >> 4;          // 0..31 k-slice
    const int ng  = tid & 15;          // 0..15 -> rows 2ng, 2ng+1
    const int ks4 = ks * 4;
    const int wv  = tid >> 6;          // wave 0..7

    // ---- stage J slice into LDS once (swizzle: k' = k ^ (4*((row>>1)&7))) ----
    {
        const f4* Jg = (const f4*)(J + (size_t)nbb * NE);
        #pragma unroll
        for (int it = 0; it < 16; ++it) {
            int fi = tid + it * 512;           // f4 index in [0, 8192)
            int r  = fi >> 8;                  // row 0..31
            int kb = (fi & 255) * 4;           // k word base
            *(f4*)&J_lds[r * 1024 + (kb ^ (((r >> 1) & 7) * 4))] = Jg[fi];
        }
    }

    // per-thread swizzled k-offset (same key for both rows of this thread)
    const int rb0 = (2 * ng + 0) * 1024;
    const int rb1 = (2 * ng + 1) * 1024;
    const int sk  = ks4 ^ ((ng & 7) * 4);

    // ---- owner state: tid<256 owns (n = nbb + (tid&31), b = pb*8 + (tid>>5)) ----
    const int on  = tid & 31;
    const int ob  = (tid >> 5) & 7;
    const int bg  = pb * 8 + ob;
    const int ng_ = nbb + on;
    float hreg = 0.f, w0 = 0.f, w1 = 0.f;
    int bt = -999;
    const float is0 = in_s[0], is1 = in_s[1];
    if (tid < 256) {
        w0 = W_in[ng_ * 2 + 0];
        w1 = W_in[ng_ * 2 + 1];
        bt = BT[bg];
    }

    int m = 0;
    #pragma unroll
    for (int i = 0; i < 8; ++i) m = max(m, BT[pb * 8 + i]);

    unsigned* slots  = bar + pb * 1024;        // 32 slots, 128B apart
    unsigned* myslot = slots + (bid & 31) * 32;

    __syncthreads();   // J_lds ready

    for (int t = 0; t < m; ++t) {
        float* __restrict__ cur = (t & 1) ? th1 : th0;
        float* __restrict__ nxt = (t & 1) ? th0 : th1;

        // ---- prefetch drive terms into regs BEFORE gate (immutable inputs) ----
        float nz = 0.f, xa = 0.f, xb = 0.f;
        if (tid < 256) {
            nz = noise[((size_t)bg * T_ + t) * NE + ng_];
            xa = X[((size_t)bg * T_ + t) * 2 + 0];
            xb = X[((size_t)bg * T_ + t) * 2 + 1];
        }

        // ---- gate: all 32 group blocks published step t-1? ----
        if (t > 0) {
            if (tid < 32) {
                unsigned* sp = slots + tid * 32;
                for (;;) {
                    unsigned v = __hip_atomic_load(sp, __ATOMIC_RELAXED,
                                                   __HIP_MEMORY_SCOPE_AGENT);
                    if (__all(v >= (unsigned)t)) break;
                    __builtin_amdgcn_s_sleep(1);
                }
            }
            __syncthreads();
        }

        // ---- stage th tile (32KB) via 8B LLC-coherent atomic loads ----
        {
            const unsigned long long* src =
                (const unsigned long long*)(cur + (size_t)pb * 8192);
            #pragma unroll
            for (int it = 0; it < 8; ++it) {
                int idx = tid + it * 512;      // u64 index in [0, 4096)
                unsigned long long v =
                    __hip_atomic_load(src + idx, __ATOMIC_RELAXED,
                                      __HIP_MEMORY_SCOPE_AGENT);
                *(unsigned long long*)&th_lds[2 * idx] = v;
            }
        }
        __syncthreads();

        // ---- MAC: 512 fma; J swizzled-LDS (2-lane/bank = free), th broadcast ----
        float a0[8] = {0.f,0.f,0.f,0.f,0.f,0.f,0.f,0.f};
        float a1[8] = {0.f,0.f,0.f,0.f,0.f,0.f,0.f,0.f};
        #pragma unroll
        for (int j = 0; j < 8; ++j) {
            const f4 j0 = *(const f4*)&J_lds[rb0 + sk + 128 * j];
            const f4 j1 = *(const f4*)&J_lds[rb1 + sk + 128 * j];
            #pragma unroll
            for (int b = 0; b < 8; ++b) {
                const f4 tv = *(const f4*)&th_lds[b * 1024 + ks4 + 128 * j];
                a0[b] = fmaf(j0.x, tv.x, a0[b]);
                a0[b] = fmaf(j0.y, tv.y, a0[b]);
                a0[b] = fmaf(j0.z, tv.z, a0[b]);
                a0[b] = fmaf(j0.w, tv.w, a0[b]);
                a1[b] = fmaf(j1.x, tv.x, a1[b]);
                a1[b] = fmaf(j1.y, tv.y, a1[b]);
                a1[b] = fmaf(j1.z, tv.z, a1[b]);
                a1[b] = fmaf(j1.w, tv.w, a1[b]);
            }
        }

        // ---- fold the wave's 4 k-slices (tid bits 4,5) via shfl_xor ----
        #pragma unroll
        for (int b = 0; b < 8; ++b) {
            a0[b] += __shfl_xor(a0[b], 16);
            a0[b] += __shfl_xor(a0[b], 32);
            a1[b] += __shfl_xor(a1[b], 16);
            a1[b] += __shfl_xor(a1[b], 32);
        }

        __syncthreads();   // MAC th-reads done -> red may overlay th_lds

        // ---- red overlay [wv][b][row] stride 33 (scalar, conflict-free) ----
        if ((tid & 48) == 0) {            // ks_local==0: 16 lanes/wave (ng 0..15)
            float* red = th_lds;
            #pragma unroll
            for (int b = 0; b < 8; ++b) {
                red[wv * 264 + b * 33 + 2 * ng + 0] = a0[b];
                red[wv * 264 + b * 33 + 2 * ng + 1] = a1[b];
            }
        }
        __syncthreads();

        // ---- owners: sum 8 wave-partials, h update, publish via LLC atomics ----
        if (tid < 256) {
            const float* red = th_lds;
            float s = 0.f;
            #pragma unroll
            for (int w = 0; w < 8; ++w)
                s += red[w * 264 + ob * 33 + on];
            float drive = s + nz + xa * is0 * w0 + xb * is1 * w1;
            hreg = 0.9f * hreg + 0.1f * drive;
            __hip_atomic_store(nxt + (size_t)bg * NE + ng_, fast_tanh(hreg),
                               __ATOMIC_RELAXED, __HIP_MEMORY_SCOPE_AGENT);
            if (bt == t + 1)
                __hip_atomic_store(last + (size_t)bg * NE + ng_, hreg,
                                   __ATOMIC_RELAXED, __HIP_MEMORY_SCOPE_AGENT);
        }
        __syncthreads();   // drains vmcnt: publishes at LLC before arrive

        // ---- arrive: own slot, release store (L2 clean -> cheap) ----
        if (tid == 0)
            __hip_atomic_store(myslot, (unsigned)(t + 1),
                               __ATOMIC_RELEASE, __HIP_MEMORY_SCOPE_AGENT);
    }
}

// ---- tail ----
__global__ __launch_bounds__(256)
void wproj(const float* __restrict__ last_enc, const float* __restrict__ W,
           const float* __restrict__ bW, float* __restrict__ dec_traj)
{
    __shared__ float tl[NE];
    const int b = blockIdx.x;
    for (int k = threadIdx.x; k < NE; k += 256)
        tl[k] = tanhf(last_enc[(size_t)b * NE + k]);
    __syncthreads();
    const int wave = threadIdx.x >> 6;
    const int lane = threadIdx.x & 63;
    for (int m = wave; m < ND; m += 4) {
        const float4* Wr = (const float4*)(W + (size_t)m * NE);
        float acc = 0.f;
        #pragma unroll
        for (int it = 0; it < 4; ++it) {
            float4 wv = Wr[lane + it * 64];
            const float* tp = &tl[(lane + it * 64) * 4];
            acc = fmaf(wv.x, tp[0], acc);
            acc = fmaf(wv.y, tp[1], acc);
            acc = fmaf(wv.z, tp[2], acc);
            acc = fmaf(wv.w, tp[3], acc);
        }
        acc += __shfl_down(acc, 32); acc += __shfl_down(acc, 16);
        acc += __shfl_down(acc, 8);  acc += __shfl_down(acc, 4);
        acc += __shfl_down(acc, 2);  acc += __shfl_down(acc, 1);
        if (lane == 0) dec_traj[(size_t)b * 4 * ND + m] = acc + bW[m];
    }
}

__global__ __launch_bounds__(256)
void dec_step(const float* __restrict__ Q, float* __restrict__ dec_traj, int s)
{
    __shared__ float prev[ND];
    const int b = blockIdx.x;
    const float* pin = dec_traj + (size_t)b * 4 * ND + (size_t)(s - 1) * ND;
    for (int k = threadIdx.x; k < ND; k += 256) prev[k] = pin[k];
    __syncthreads();
    const int wave = threadIdx.x >> 6;
    const int lane = threadIdx.x & 63;
    for (int m = wave; m < ND; m += 4) {
        const float4* Qr = (const float4*)(Q + (size_t)m * ND);
        float acc = 0.f;
        #pragma unroll
        for (int it = 0; it < 2; ++it) {
            float4 qv = Qr[lane + it * 64];
            const float* tp = &prev[(lane + it * 64) * 4];
            acc = fmaf(qv.x, tp[0], acc);
            acc = fmaf(qv.y, tp[1], acc);
            acc = fmaf(qv.z, tp[2], acc);
            acc = fmaf(qv.w, tp[3], acc);
        }
        acc += __shfl_down(acc, 32); acc += __shfl_down(acc, 16);
        acc += __shfl_down(acc, 8);  acc += __shfl_down(acc, 4);
        acc += __shfl_down(acc, 2);  acc += __shfl_down(acc, 1);
        if (lane == 0)
            dec_traj[(size_t)b * 4 * ND + (size_t)s * ND + m] = acc;
    }
}

__global__ __launch_bounds__(256)
void out_proj(const float* __restrict__ dec_traj, const float* __restrict__ W_out,
              const float* __restrict__ out_s, float* __restrict__ Out)
{
    const int b = blockIdx.x;
    const int s = threadIdx.x >> 6;
    const int lane = threadIdx.x & 63;
    const float4* dp = (const float4*)(dec_traj + (size_t)b * 4 * ND + (size_t)s * ND);
    const float4* w0 = (const float4*)(W_out);
    const float4* w1 = (const float4*)(W_out + ND);
    float a0 = 0.f, a1 = 0.f;
    #pragma unroll
    for (int it = 0; it < 2; ++it) {
        float4 v  = dp[lane + it * 64];
        float4 u0 = w0[lane + it * 64];
        float4 u1 = w1[lane + it * 64];
        a0 = fmaf(v.x, u0.x, fmaf(v.y, u0.y, fmaf(v.z, u0.z, fmaf(v.w, u0.w, a0))));
        a1 = fmaf(v.x, u1.x, fmaf(v.y, u1.y, fmaf(v.z, u1.z, fmaf(v.w, u1.w, a1))));
    }
    for (int off = 32; off; off >>= 1) {
        a0 += __shfl_down(a0, off);
        a1 += __shfl_down(a1, off);
    }
    if (lane == 0) {
        Out[(size_t)b * 8 + s * 2 + 0] = out_s[0] * a0;
        Out[(size_t)b * 8 + s * 2 + 1] = out_s[1] * a1;
    }
}

extern "C" void kernel_launch(void* const* d_in, const int* in_sizes, int n_in,
                              void* d_out, int out_size, void* d_ws, size_t ws_size,
                              hipStream_t stream) {
    const float* X      = (const float*)d_in[0];
    const float* noise  = (const float*)d_in[1];
    const float* W_in   = (const float*)d_in[2];
    const float* J      = (const float*)d_in[3];
    const float* W      = (const float*)d_in[4];
    const float* bW     = (const float*)d_in[5];
    const float* Q      = (const float*)d_in[6];
    const float* W_out  = (const float*)d_in[7];
    const float* in_s   = (const float*)d_in[8];
    const float* out_s  = (const float*)d_in[9];
    const int*   BT     = (const int*)d_in[10];

    float* ws   = (float*)d_ws;
    float* th0  = ws + WS_TH0;
    float* th1  = ws + WS_TH1;
    float* last = ws + WS_LAST;
    unsigned* bar = (unsigned*)(ws + WS_BAR);

    float* out      = (float*)d_out;               // dec_traj (64,4,512)
    float* out_tail = out + (size_t)B_ * 4 * ND;   // Output (64,4,2)

    init_ws<<<200, 256, 0, stream>>>((float4*)ws);
    enc_persist<<<256, 512, 0, stream>>>(X, noise, W_in, J, in_s, BT,
                                         th0, th1, last, bar);
    wproj<<<B_, 256, 0, stream>>>(last, W, bW, out);
    for (int s = 1; s <= 3; ++s)
        dec_step<<<B_, 256, 0, stream>>>(Q, out, s);
    out_proj<<<B_, 256, 0, stream>>>(out, W_out, out_s, out_tail);
}